// Round 3
// baseline (271.907 us; speedup 1.0000x reference)
//
#include <hip/hip_runtime.h>
#include <hip/hip_bf16.h>

typedef float f32x4 __attribute__((ext_vector_type(4)));
typedef __bf16 bf16x8 __attribute__((ext_vector_type(8)));
typedef __bf16 bf16x4 __attribute__((ext_vector_type(4)));

// ---------------- weight prep: G[k2][n][cp] = sum_c fc_w[n,c] * w2[c,cp,k2] ----
__global__ __launch_bounds__(256) void prep_g(const float* __restrict__ fcw,
                                              const float* __restrict__ w2,
                                              float* __restrict__ G) {
  int tid = blockIdx.x * 256 + threadIdx.x;   // 24576 threads
  int cp = tid & 255;
  int rest = tid >> 8;       // 0..95
  int n = rest & 31;
  int k2 = rest >> 5;        // 0..2
  float acc = 0.f;
  for (int c = 0; c < 256; ++c)
    acc = fmaf(fcw[n * 256 + c], w2[(c * 256 + cp) * 3 + k2], acc);
  G[(k2 * 32 + n) * 256 + cp] = acc;
}

// ---------------- Wf[n][e][kk] (packed bf16 in MFMA B-frag layout), C0, CT, biases
__global__ __launch_bounds__(256) void prep_wf(const float* __restrict__ G,
                                               const float* __restrict__ w1,
                                               const float* __restrict__ b1,
                                               const float* __restrict__ b2,
                                               const float* __restrict__ fcw,
                                               const float* __restrict__ fcb,
                                               __bf16* __restrict__ wfb,
                                               float* __restrict__ C0,
                                               float* __restrict__ CT,
                                               float* __restrict__ bias_tot,
                                               float* __restrict__ c0v,
                                               float* __restrict__ cTv) {
  int tid = blockIdx.x * 256 + threadIdx.x;
  if (tid < 40960) {                 // Wf part: tid = (e*5 + kk)*32 + n
    int n = tid & 31;
    int r = tid >> 5;                // 0..1279
    int kk = r % 5;
    int e = r / 5;
    float acc = 0.f;
    #pragma unroll
    for (int k2 = 0; k2 < 3; ++k2) {
      int k1 = kk - k2;
      if (k1 < 0 || k1 > 2) continue;
      const float* g = G + (k2 * 32 + n) * 256;
      for (int cp = 0; cp < 256; ++cp)
        acc = fmaf(g[cp], w1[cp * 768 + e * 3 + k1], acc);
    }
    // pack into B-frag layout for mfma_f32_16x16x32_bf16:
    // B[k=e][j=kk*32+n], frag: lane = (j&15) | (((e>>3)&3)<<4), elem r = e&7
    int j = kk * 32 + n;
    int jt = j >> 4, jl = j & 15;
    int et = e >> 5, el = e & 31;
    int lane = jl | ((el >> 3) << 4);
    int rr = el & 7;
    wfb[((jt * 8 + et) * 64 + lane) * 8 + rr] = (__bf16)acc;
  } else if (tid < 57344) {          // C0 / CT
    int t2 = tid - 40960;
    int which = (t2 >= 8192);
    if (which) t2 -= 8192;
    int n = t2 & 31;
    int e = t2 >> 5;
    const float* g = G + ((which ? 2 : 0) * 32 + n) * 256;
    int k1 = which ? 0 : 2;
    float acc = 0.f;
    for (int cp = 0; cp < 256; ++cp)
      acc = fmaf(g[cp], w1[cp * 768 + e * 3 + k1], acc);
    (which ? CT : C0)[n * 256 + e] = acc;
  } else if (tid < 57376) {          // biases
    int n = tid - 57344;
    float bt = fcb[n];
    for (int c = 0; c < 256; ++c) bt = fmaf(fcw[n * 256 + c], b2[c], bt);
    float s0 = 0.f, s1 = 0.f, s2 = 0.f;
    const float* g0 = G + (0 * 32 + n) * 256;
    const float* g1 = G + (1 * 32 + n) * 256;
    const float* g2 = G + (2 * 32 + n) * 256;
    for (int cp = 0; cp < 256; ++cp) {
      s0 = fmaf(g0[cp], b1[cp], s0);
      s1 = fmaf(g1[cp], b1[cp], s1);
      s2 = fmaf(g2[cp], b1[cp], s2);
    }
    bias_tot[n] = bt + s0 + s1 + s2;
    c0v[n] = s0;
    cTv[n] = s2;
  }
}

// ---------------- boundary corrections: corr[which][b][n] = cv[n] + dot(C[n,:], emb[v,:])
__global__ __launch_bounds__(256) void corr_k(const int* __restrict__ idx,
                                              const float* __restrict__ emb,
                                              const float* __restrict__ C0,
                                              const float* __restrict__ CT,
                                              const float* __restrict__ c0v,
                                              const float* __restrict__ cTv,
                                              float* __restrict__ corr) {
  __shared__ float red[256];
  int b = blockIdx.x >> 1;
  int which = blockIdx.x & 1;
  int n = threadIdx.x & 31;
  int part = threadIdx.x >> 5;   // 0..7
  int v = idx[b * 2048 + (which ? 2047 : 0)];
  const float* C = which ? CT : C0;
  const float* er = emb + v * 256 + part * 32;
  const float* cr = C + n * 256 + part * 32;
  float s = 0.f;
  #pragma unroll
  for (int e = 0; e < 32; ++e) s = fmaf(cr[e], er[e], s);
  red[threadIdx.x] = s;
  __syncthreads();
  if (part == 0) {
    float tot = (which ? cTv : c0v)[n];
    #pragma unroll
    for (int p = 0; p < 8; ++p) tot += red[p * 32 + n];
    corr[(which * 64 + b) * 32 + n] = tot;
  }
}

// ---------------- P[v][kk][n] = sum_e emb[v,e] * Wf[n,e,kk]  (bf16 MFMA GEMM, bf16 out)
__global__ __launch_bounds__(256) void p_table(const float* __restrict__ emb,
                                               const __bf16* __restrict__ wfb,
                                               __bf16* __restrict__ P) {
  int lane = threadIdx.x & 63;
  int mt = blockIdx.x * 4 + (threadIdx.x >> 6);  // 0..1999
  int ln = lane & 15;
  int q = lane >> 4;
  int m = mt * 16 + ln;
  f32x4 acc[10];
  #pragma unroll
  for (int jt = 0; jt < 10; ++jt) acc[jt] = (f32x4){0.f, 0.f, 0.f, 0.f};
  const float* arow = emb + m * 256 + q * 8;
  #pragma unroll
  for (int et = 0; et < 8; ++et) {
    f32x4 a0 = *(const f32x4*)(arow + et * 32);
    f32x4 a1 = *(const f32x4*)(arow + et * 32 + 4);
    bf16x8 af;
    af[0] = (__bf16)a0[0]; af[1] = (__bf16)a0[1];
    af[2] = (__bf16)a0[2]; af[3] = (__bf16)a0[3];
    af[4] = (__bf16)a1[0]; af[5] = (__bf16)a1[1];
    af[6] = (__bf16)a1[2]; af[7] = (__bf16)a1[3];
    #pragma unroll
    for (int jt = 0; jt < 10; ++jt) {
      bf16x8 bfr = *(const bf16x8*)(wfb + ((jt * 8 + et) * 64 + lane) * 8);
      acc[jt] = __builtin_amdgcn_mfma_f32_16x16x32_bf16(af, bfr, acc[jt], 0, 0, 0);
    }
  }
  // C layout: col = lane&15, row = (lane>>4)*4 + reg
  #pragma unroll
  for (int jt = 0; jt < 10; ++jt) {
    __bf16* pp = P + (mt * 16 + q * 4) * 160 + jt * 16 + ln;
    pp[0]   = (__bf16)acc[jt][0];
    pp[160] = (__bf16)acc[jt][1];
    pp[320] = (__bf16)acc[jt][2];
    pp[480] = (__bf16)acc[jt][3];
  }
}

// ---------------- logits -> Lexp[b][t][n] = exp(logit) * 2^-5   (2 t per thread)
__global__ __launch_bounds__(256) void logits_k(const int* __restrict__ idx,
                                                const __bf16* __restrict__ P,
                                                const float* __restrict__ bias_tot,
                                                const float* __restrict__ corr,
                                                float* __restrict__ L) {
  int tid = blockIdx.x * 256 + threadIdx.x;    // 2^19 threads
  int q = tid & 7;
  int tp = (tid >> 3) & 1023;
  int b = tid >> 13;
  int t0 = tp * 2;
  const int* ib = idx + b * 2048;
  f32x4 bias = *(const f32x4*)(bias_tot + q * 4);
  f32x4 acc0 = bias, acc1 = bias;
  #pragma unroll
  for (int j = 0; j < 6; ++j) {
    int tt = t0 + j - 2;
    if (tt < 0 || tt > 2047) continue;
    int v = ib[tt];
    const __bf16* pr = P + v * 160 + q * 4;
    if (j < 5) {                       // contributes to t0 with k=j
      bf16x4 pv = *(const bf16x4*)(pr + j * 32);
      acc0[0] += (float)pv[0]; acc0[1] += (float)pv[1];
      acc0[2] += (float)pv[2]; acc0[3] += (float)pv[3];
    }
    if (j >= 1) {                      // contributes to t1 with k=j-1
      bf16x4 pv = *(const bf16x4*)(pr + (j - 1) * 32);
      acc1[0] += (float)pv[0]; acc1[1] += (float)pv[1];
      acc1[2] += (float)pv[2]; acc1[3] += (float)pv[3];
    }
  }
  if (t0 == 0)        acc0 -= *(const f32x4*)(corr + b * 32 + q * 4);
  if (t0 + 1 == 2047) acc1 -= *(const f32x4*)(corr + (64 + b) * 32 + q * 4);
  f32x4 r0, r1;
  r0[0] = __expf(acc0[0]) * 0.03125f;
  r0[1] = __expf(acc0[1]) * 0.03125f;
  r0[2] = __expf(acc0[2]) * 0.03125f;
  r0[3] = __expf(acc0[3]) * 0.03125f;
  r1[0] = __expf(acc1[0]) * 0.03125f;
  r1[1] = __expf(acc1[1]) * 0.03125f;
  r1[2] = __expf(acc1[2]) * 0.03125f;
  r1[3] = __expf(acc1[3]) * 0.03125f;
  float* Lb = L + (b * 2048 + t0) * 32 + q * 4;
  *(f32x4*)(Lb) = r0;
  *(f32x4*)(Lb + 32) = r1;
}

// ---------------- CRF stage 1: one wave per (b, chunk): 32-step 32x32 MFMA chain
// Transposed form: S <- (D_t * Texp^T) * S, S0 = I; final M_c = S^T.
__global__ __launch_bounds__(256) void crf_stage1(const float* __restrict__ Lexp,
                                                  const float* __restrict__ trans,
                                                  float* __restrict__ Pc) {
  __shared__ __bf16 sl[4][32 * 40];   // wave-private S scratch, padded stride 40
  int lane = threadIdx.x & 63;
  int w = threadIdx.x >> 6;
  int chain = blockIdx.x * 4 + w;     // 0..4095
  int c = chain >> 6;                 // chunk 0..63
  int b = chain & 63;
  int ln = lane & 15;
  int q = lane >> 4;
  // Texp^T rows for A: tA[it][e] = exp(trans[q*8+e][it*16+ln])
  float tA0[8], tA1[8];
  #pragma unroll
  for (int e = 0; e < 8; ++e) {
    tA0[e] = __expf(trans[(q * 8 + e) * 32 + ln]);
    tA1[e] = __expf(trans[(q * 8 + e) * 32 + 16 + ln]);
  }
  // init B frags: S = I
  bf16x8 bf0, bf1;
  #pragma unroll
  for (int e = 0; e < 8; ++e) {
    int k = q * 8 + e;
    bf0[e] = (k == ln) ? (__bf16)1.0f : (__bf16)0.0f;
    bf1[e] = (k == 16 + ln) ? (__bf16)1.0f : (__bf16)0.0f;
  }
  int tstart = c * 32 + 1;
  int nsteps = (c == 63) ? 31 : 32;
  const float* Le = Lexp + (b * 2048 + tstart) * 32;
  __bf16* myS = &sl[w][0];
  f32x4 c00, c01, c10, c11;
  float sc0 = Le[ln], sc1 = Le[ln + 16];
  for (int s = 0; s < nsteps; ++s) {
    float nsc0 = 0.f, nsc1 = 0.f;
    if (s + 1 < nsteps) {              // prefetch next-step scales
      nsc0 = Le[(s + 1) * 32 + ln];
      nsc1 = Le[(s + 1) * 32 + ln + 16];
    }
    bf16x8 a0, a1;
    #pragma unroll
    for (int e = 0; e < 8; ++e) {
      a0[e] = (__bf16)(sc0 * tA0[e]);
      a1[e] = (__bf16)(sc1 * tA1[e]);
    }
    f32x4 z = {0.f, 0.f, 0.f, 0.f};
    c00 = __builtin_amdgcn_mfma_f32_16x16x32_bf16(a0, bf0, z, 0, 0, 0);
    c01 = __builtin_amdgcn_mfma_f32_16x16x32_bf16(a0, bf1, z, 0, 0, 0);
    c10 = __builtin_amdgcn_mfma_f32_16x16x32_bf16(a1, bf0, z, 0, 0, 0);
    c11 = __builtin_amdgcn_mfma_f32_16x16x32_bf16(a1, bf1, z, 0, 0, 0);
    if (s + 1 < nsteps) {
      // store S' transposed into LDS: myS[col*40 + row]
      bf16x4 w00, w01, w10, w11;
      #pragma unroll
      for (int r = 0; r < 4; ++r) {
        w00[r] = (__bf16)c00[r]; w01[r] = (__bf16)c01[r];
        w10[r] = (__bf16)c10[r]; w11[r] = (__bf16)c11[r];
      }
      *(bf16x4*)(myS + (ln) * 40      + q * 4)      = w00;
      *(bf16x4*)(myS + (16 + ln) * 40 + q * 4)      = w01;
      *(bf16x4*)(myS + (ln) * 40      + 16 + q * 4) = w10;
      *(bf16x4*)(myS + (16 + ln) * 40 + 16 + q * 4) = w11;
      bf0 = *(const bf16x8*)(myS + (ln) * 40 + q * 8);
      bf1 = *(const bf16x8*)(myS + (16 + ln) * 40 + q * 8);
    }
    sc0 = nsc0; sc1 = nsc1;
  }
  // Pc[b][c][i][j] = S[j][i]
  float* dst = Pc + ((b * 64 + c) * 32) * 32;
  *(f32x4*)(dst + (ln) * 32      + q * 4)      = c00;
  *(f32x4*)(dst + (16 + ln) * 32 + q * 4)      = c01;
  *(f32x4*)(dst + (ln) * 32      + 16 + q * 4) = c10;
  *(f32x4*)(dst + (16 + ln) * 32 + 16 + q * 4) = c11;
}

// ---------------- CRF stage 2: per-batch sequential combine of 64 chunk matrices
__global__ __launch_bounds__(64) void crf_stage2(const float* __restrict__ Lexp,
                                                 const float* __restrict__ Pc,
                                                 const float* __restrict__ start_t,
                                                 const float* __restrict__ end_t,
                                                 float* __restrict__ out) {
  int b = blockIdx.x;
  int j = threadIdx.x & 31;
  float u = __expf(start_t[j]) * Lexp[b * 2048 * 32 + j] * 32.f;
  float logacc = 0.f;
  for (int c = 0; c < 64; ++c) {
    const float* M = Pc + ((b * 64 + c) * 32) * 32;
    float nu0 = 0.f, nu1 = 0.f, nu2 = 0.f, nu3 = 0.f;
    #pragma unroll
    for (int k = 0; k < 32; k += 4) {
      nu0 = fmaf(__shfl(u, k,     32), M[(k)     * 32 + j], nu0);
      nu1 = fmaf(__shfl(u, k + 1, 32), M[(k + 1) * 32 + j], nu1);
      nu2 = fmaf(__shfl(u, k + 2, 32), M[(k + 2) * 32 + j], nu2);
      nu3 = fmaf(__shfl(u, k + 3, 32), M[(k + 3) * 32 + j], nu3);
    }
    float nu = (nu0 + nu1) + (nu2 + nu3);
    float ssum = nu;
    #pragma unroll
    for (int o = 1; o < 32; o <<= 1) ssum += __shfl_xor(ssum, o, 32);
    u = nu / ssum;
    logacc += logf(ssum);
  }
  float term = u * __expf(end_t[j]);
  #pragma unroll
  for (int o = 1; o < 32; o <<= 1) term += __shfl_xor(term, o, 32);
  if (threadIdx.x == 0)
    out[b] = logacc + logf(term) + (float)(2047.0 * 5.0 * 0.69314718055994530942);
}

extern "C" void kernel_launch(void* const* d_in, const int* in_sizes, int n_in,
                              void* d_out, int out_size, void* d_ws, size_t ws_size,
                              hipStream_t stream) {
  const int*   idx  = (const int*)d_in[0];
  const float* emb  = (const float*)d_in[1];
  const float* w1   = (const float*)d_in[2];
  const float* b1   = (const float*)d_in[3];
  const float* w2   = (const float*)d_in[4];
  const float* b2   = (const float*)d_in[5];
  const float* fcw  = (const float*)d_in[6];
  const float* fcb  = (const float*)d_in[7];
  const float* trn  = (const float*)d_in[8];
  const float* st   = (const float*)d_in[9];
  const float* en   = (const float*)d_in[10];

  char* ws = (char*)d_ws;
  __bf16* P     = (__bf16*)(ws + 0);           // 10,240,000 B
  float*  L     = (float*)(ws + 10240000);     // 16,777,216 B  (Lexp)
  float*  Pc    = (float*)(ws + 27017216);     // 16,777,216 B
  __bf16* WfB   = (__bf16*)(ws + 43794432);    //     81,920 B
  float*  G     = (float*)(ws + 43876352);     //     98,304 B
  float*  C0    = (float*)(ws + 43974656);     //     32,768 B
  float*  CT    = (float*)(ws + 44007424);     //     32,768 B
  float*  bias  = (float*)(ws + 44040192);     //        128 B
  float*  c0v   = (float*)(ws + 44040320);     //        128 B
  float*  cTv   = (float*)(ws + 44040448);     //        128 B
  float*  corr  = (float*)(ws + 44040576);     //     16,384 B
  // total ws need ~44.06 MB

  prep_g    <<<96,   256, 0, stream>>>(fcw, w2, G);
  prep_wf   <<<225,  256, 0, stream>>>(G, w1, b1, b2, fcw, fcb, WfB, C0, CT, bias, c0v, cTv);
  corr_k    <<<128,  256, 0, stream>>>(idx, emb, C0, CT, c0v, cTv, corr);
  p_table   <<<500,  256, 0, stream>>>(emb, WfB, P);
  logits_k  <<<2048, 256, 0, stream>>>(idx, P, bias, corr, L);
  crf_stage1<<<1024, 256, 0, stream>>>(L, trn, Pc);
  crf_stage2<<<64,    64, 0, stream>>>(L, Pc, st, en, (float*)d_out);
}

// Round 4
// 248.504 us; speedup vs baseline: 1.0942x; 1.0942x over previous
//
#include <hip/hip_runtime.h>
#include <hip/hip_bf16.h>

typedef float f32x4 __attribute__((ext_vector_type(4)));
typedef __bf16 bf16x8 __attribute__((ext_vector_type(8)));
typedef __bf16 bf16x4 __attribute__((ext_vector_type(4)));

// ---------------- weight prep: G[k2][n][cp] = sum_c fc_w[n,c] * w2[c,cp,k2] ----
__global__ __launch_bounds__(256) void prep_g(const float* __restrict__ fcw,
                                              const float* __restrict__ w2,
                                              float* __restrict__ G) {
  int tid = blockIdx.x * 256 + threadIdx.x;   // 24576 threads
  int cp = tid & 255;
  int rest = tid >> 8;       // 0..95
  int n = rest & 31;
  int k2 = rest >> 5;        // 0..2
  float acc = 0.f;
  for (int c = 0; c < 256; ++c)
    acc = fmaf(fcw[n * 256 + c], w2[(c * 256 + cp) * 3 + k2], acc);
  G[(k2 * 32 + n) * 256 + cp] = acc;
}

// ---------------- Wf[n][e][kk] (packed bf16 in MFMA B-frag layout), C0, CT, biases
__global__ __launch_bounds__(256) void prep_wf(const float* __restrict__ G,
                                               const float* __restrict__ w1,
                                               const float* __restrict__ b1,
                                               const float* __restrict__ b2,
                                               const float* __restrict__ fcw,
                                               const float* __restrict__ fcb,
                                               __bf16* __restrict__ wfb,
                                               float* __restrict__ C0,
                                               float* __restrict__ CT,
                                               float* __restrict__ bias_tot,
                                               float* __restrict__ c0v,
                                               float* __restrict__ cTv) {
  int tid = blockIdx.x * 256 + threadIdx.x;
  if (tid < 40960) {                 // Wf part: tid = (e*5 + kk)*32 + n
    int n = tid & 31;
    int r = tid >> 5;                // 0..1279
    int kk = r % 5;
    int e = r / 5;
    float acc = 0.f;
    #pragma unroll
    for (int k2 = 0; k2 < 3; ++k2) {
      int k1 = kk - k2;
      if (k1 < 0 || k1 > 2) continue;
      const float* g = G + (k2 * 32 + n) * 256;
      for (int cp = 0; cp < 256; ++cp)
        acc = fmaf(g[cp], w1[cp * 768 + e * 3 + k1], acc);
    }
    // pack into B-frag layout for mfma_f32_16x16x32_bf16:
    // B[k=e][j=kk*32+n], frag: lane = (j&15) | (((e>>3)&3)<<4), elem r = e&7
    int j = kk * 32 + n;
    int jt = j >> 4, jl = j & 15;
    int et = e >> 5, el = e & 31;
    int lane = jl | ((el >> 3) << 4);
    int rr = el & 7;
    wfb[((jt * 8 + et) * 64 + lane) * 8 + rr] = (__bf16)acc;
  } else if (tid < 57344) {          // C0 / CT
    int t2 = tid - 40960;
    int which = (t2 >= 8192);
    if (which) t2 -= 8192;
    int n = t2 & 31;
    int e = t2 >> 5;
    const float* g = G + ((which ? 2 : 0) * 32 + n) * 256;
    int k1 = which ? 0 : 2;
    float acc = 0.f;
    for (int cp = 0; cp < 256; ++cp)
      acc = fmaf(g[cp], w1[cp * 768 + e * 3 + k1], acc);
    (which ? CT : C0)[n * 256 + e] = acc;
  } else if (tid < 57376) {          // biases
    int n = tid - 57344;
    float bt = fcb[n];
    for (int c = 0; c < 256; ++c) bt = fmaf(fcw[n * 256 + c], b2[c], bt);
    float s0 = 0.f, s1 = 0.f, s2 = 0.f;
    const float* g0 = G + (0 * 32 + n) * 256;
    const float* g1 = G + (1 * 32 + n) * 256;
    const float* g2 = G + (2 * 32 + n) * 256;
    for (int cp = 0; cp < 256; ++cp) {
      s0 = fmaf(g0[cp], b1[cp], s0);
      s1 = fmaf(g1[cp], b1[cp], s1);
      s2 = fmaf(g2[cp], b1[cp], s2);
    }
    bias_tot[n] = bt + s0 + s1 + s2;
    c0v[n] = s0;
    cTv[n] = s2;
  }
}

// ---------------- boundary corrections: corr[which][b][n] = cv[n] + dot(C[n,:], emb[v,:])
__global__ __launch_bounds__(256) void corr_k(const int* __restrict__ idx,
                                              const float* __restrict__ emb,
                                              const float* __restrict__ C0,
                                              const float* __restrict__ CT,
                                              const float* __restrict__ c0v,
                                              const float* __restrict__ cTv,
                                              float* __restrict__ corr) {
  __shared__ float red[256];
  int b = blockIdx.x >> 1;
  int which = blockIdx.x & 1;
  int n = threadIdx.x & 31;
  int part = threadIdx.x >> 5;   // 0..7
  int v = idx[b * 2048 + (which ? 2047 : 0)];
  const float* C = which ? CT : C0;
  const float* er = emb + v * 256 + part * 32;
  const float* cr = C + n * 256 + part * 32;
  float s = 0.f;
  #pragma unroll
  for (int e = 0; e < 32; ++e) s = fmaf(cr[e], er[e], s);
  red[threadIdx.x] = s;
  __syncthreads();
  if (part == 0) {
    float tot = (which ? cTv : c0v)[n];
    #pragma unroll
    for (int p = 0; p < 8; ++p) tot += red[p * 32 + n];
    corr[(which * 64 + b) * 32 + n] = tot;
  }
}

// ---------------- P[v][kk][n] = sum_e emb[v,e] * Wf[n,e,kk]  (bf16 MFMA GEMM, bf16 out)
__global__ __launch_bounds__(256) void p_table(const float* __restrict__ emb,
                                               const __bf16* __restrict__ wfb,
                                               __bf16* __restrict__ P) {
  int lane = threadIdx.x & 63;
  int mt = blockIdx.x * 4 + (threadIdx.x >> 6);  // 0..1999
  int ln = lane & 15;
  int q = lane >> 4;
  int m = mt * 16 + ln;
  f32x4 acc[10];
  #pragma unroll
  for (int jt = 0; jt < 10; ++jt) acc[jt] = (f32x4){0.f, 0.f, 0.f, 0.f};
  const float* arow = emb + m * 256 + q * 8;
  #pragma unroll
  for (int et = 0; et < 8; ++et) {
    f32x4 a0 = *(const f32x4*)(arow + et * 32);
    f32x4 a1 = *(const f32x4*)(arow + et * 32 + 4);
    bf16x8 af;
    af[0] = (__bf16)a0[0]; af[1] = (__bf16)a0[1];
    af[2] = (__bf16)a0[2]; af[3] = (__bf16)a0[3];
    af[4] = (__bf16)a1[0]; af[5] = (__bf16)a1[1];
    af[6] = (__bf16)a1[2]; af[7] = (__bf16)a1[3];
    #pragma unroll
    for (int jt = 0; jt < 10; ++jt) {
      bf16x8 bfr = *(const bf16x8*)(wfb + ((jt * 8 + et) * 64 + lane) * 8);
      acc[jt] = __builtin_amdgcn_mfma_f32_16x16x32_bf16(af, bfr, acc[jt], 0, 0, 0);
    }
  }
  // C layout: col = lane&15, row = (lane>>4)*4 + reg
  #pragma unroll
  for (int jt = 0; jt < 10; ++jt) {
    __bf16* pp = P + (mt * 16 + q * 4) * 160 + jt * 16 + ln;
    pp[0]   = (__bf16)acc[jt][0];
    pp[160] = (__bf16)acc[jt][1];
    pp[320] = (__bf16)acc[jt][2];
    pp[480] = (__bf16)acc[jt][3];
  }
}

// ---------------- logits -> Lexp[b][t][n] = exp(logit) * 2^-5   (2 t per thread)
__global__ __launch_bounds__(256) void logits_k(const int* __restrict__ idx,
                                                const __bf16* __restrict__ P,
                                                const float* __restrict__ bias_tot,
                                                const float* __restrict__ corr,
                                                float* __restrict__ L) {
  int tid = blockIdx.x * 256 + threadIdx.x;    // 2^19 threads
  int q = tid & 7;
  int tp = (tid >> 3) & 1023;
  int b = tid >> 13;
  int t0 = tp * 2;
  const int* ib = idx + b * 2048;
  f32x4 bias = *(const f32x4*)(bias_tot + q * 4);
  f32x4 acc0 = bias, acc1 = bias;
  #pragma unroll
  for (int j = 0; j < 6; ++j) {
    int tt = t0 + j - 2;
    if (tt < 0 || tt > 2047) continue;
    int v = ib[tt];
    const __bf16* pr = P + v * 160 + q * 4;
    if (j < 5) {                       // contributes to t0 with k=j
      bf16x4 pv = *(const bf16x4*)(pr + j * 32);
      acc0[0] += (float)pv[0]; acc0[1] += (float)pv[1];
      acc0[2] += (float)pv[2]; acc0[3] += (float)pv[3];
    }
    if (j >= 1) {                      // contributes to t1 with k=j-1
      bf16x4 pv = *(const bf16x4*)(pr + (j - 1) * 32);
      acc1[0] += (float)pv[0]; acc1[1] += (float)pv[1];
      acc1[2] += (float)pv[2]; acc1[3] += (float)pv[3];
    }
  }
  if (t0 == 0)        acc0 -= *(const f32x4*)(corr + b * 32 + q * 4);
  if (t0 + 1 == 2047) acc1 -= *(const f32x4*)(corr + (64 + b) * 32 + q * 4);
  f32x4 r0, r1;
  r0[0] = __expf(acc0[0]) * 0.03125f;
  r0[1] = __expf(acc0[1]) * 0.03125f;
  r0[2] = __expf(acc0[2]) * 0.03125f;
  r0[3] = __expf(acc0[3]) * 0.03125f;
  r1[0] = __expf(acc1[0]) * 0.03125f;
  r1[1] = __expf(acc1[1]) * 0.03125f;
  r1[2] = __expf(acc1[2]) * 0.03125f;
  r1[3] = __expf(acc1[3]) * 0.03125f;
  float* Lb = L + (b * 2048 + t0) * 32 + q * 4;
  *(f32x4*)(Lb) = r0;
  *(f32x4*)(Lb + 32) = r1;
}

// ---------------- CRF stage 1: one wave per (b, chunk): 32-step 32x32 MFMA chain
// Transposed form: S <- (D_t * Texp^T) * S, S0 = I; final M_c = S^T.
__global__ __launch_bounds__(256) void crf_stage1(const float* __restrict__ Lexp,
                                                  const float* __restrict__ trans,
                                                  float* __restrict__ Pc) {
  __shared__ __bf16 sl[4][32 * 40];   // wave-private S scratch, padded stride 40
  int lane = threadIdx.x & 63;
  int w = threadIdx.x >> 6;
  int chain = blockIdx.x * 4 + w;     // 0..4095
  int c = chain >> 6;                 // chunk 0..63
  int b = chain & 63;
  int ln = lane & 15;
  int q = lane >> 4;
  // Texp^T rows for A: tA[it][e] = exp(trans[q*8+e][it*16+ln])
  float tA0[8], tA1[8];
  #pragma unroll
  for (int e = 0; e < 8; ++e) {
    tA0[e] = __expf(trans[(q * 8 + e) * 32 + ln]);
    tA1[e] = __expf(trans[(q * 8 + e) * 32 + 16 + ln]);
  }
  // init B frags: S = I
  bf16x8 bf0, bf1;
  #pragma unroll
  for (int e = 0; e < 8; ++e) {
    int k = q * 8 + e;
    bf0[e] = (k == ln) ? (__bf16)1.0f : (__bf16)0.0f;
    bf1[e] = (k == 16 + ln) ? (__bf16)1.0f : (__bf16)0.0f;
  }
  int tstart = c * 32 + 1;
  int nsteps = (c == 63) ? 31 : 32;
  const float* Le = Lexp + (b * 2048 + tstart) * 32;
  __bf16* myS = &sl[w][0];
  f32x4 c00, c01, c10, c11;
  float sc0 = Le[ln], sc1 = Le[ln + 16];
  for (int s = 0; s < nsteps; ++s) {
    float nsc0 = 0.f, nsc1 = 0.f;
    if (s + 1 < nsteps) {              // prefetch next-step scales
      nsc0 = Le[(s + 1) * 32 + ln];
      nsc1 = Le[(s + 1) * 32 + ln + 16];
    }
    bf16x8 a0, a1;
    #pragma unroll
    for (int e = 0; e < 8; ++e) {
      a0[e] = (__bf16)(sc0 * tA0[e]);
      a1[e] = (__bf16)(sc1 * tA1[e]);
    }
    f32x4 z = {0.f, 0.f, 0.f, 0.f};
    c00 = __builtin_amdgcn_mfma_f32_16x16x32_bf16(a0, bf0, z, 0, 0, 0);
    c01 = __builtin_amdgcn_mfma_f32_16x16x32_bf16(a0, bf1, z, 0, 0, 0);
    c10 = __builtin_amdgcn_mfma_f32_16x16x32_bf16(a1, bf0, z, 0, 0, 0);
    c11 = __builtin_amdgcn_mfma_f32_16x16x32_bf16(a1, bf1, z, 0, 0, 0);
    if (s + 1 < nsteps) {
      // store S' transposed into LDS: myS[col*40 + row]
      bf16x4 w00, w01, w10, w11;
      #pragma unroll
      for (int r = 0; r < 4; ++r) {
        w00[r] = (__bf16)c00[r]; w01[r] = (__bf16)c01[r];
        w10[r] = (__bf16)c10[r]; w11[r] = (__bf16)c11[r];
      }
      *(bf16x4*)(myS + (ln) * 40      + q * 4)      = w00;
      *(bf16x4*)(myS + (16 + ln) * 40 + q * 4)      = w01;
      *(bf16x4*)(myS + (ln) * 40      + 16 + q * 4) = w10;
      *(bf16x4*)(myS + (16 + ln) * 40 + 16 + q * 4) = w11;
      bf0 = *(const bf16x8*)(myS + (ln) * 40 + q * 8);
      bf1 = *(const bf16x8*)(myS + (16 + ln) * 40 + q * 8);
    }
    sc0 = nsc0; sc1 = nsc1;
  }
  // Pc[b][c][i][j] = S[j][i]
  float* dst = Pc + ((b * 64 + c) * 32) * 32;
  *(f32x4*)(dst + (ln) * 32      + q * 4)      = c00;
  *(f32x4*)(dst + (16 + ln) * 32 + q * 4)      = c01;
  *(f32x4*)(dst + (ln) * 32      + 16 + q * 4) = c10;
  *(f32x4*)(dst + (16 + ln) * 32 + 16 + q * 4) = c11;
}

// ---------------- CRF stage 2: per-batch sequential combine of 64 chunk matrices
// One 256-thread block per batch; LDS double-buffer pipelines the M_c loads
// (u-independent) across the serial shuffle-fma chain; all 4 waves compute
// redundantly to keep the block divergence-free.
__global__ __launch_bounds__(256) void crf_stage2(const float* __restrict__ Lexp,
                                                  const float* __restrict__ Pc,
                                                  const float* __restrict__ start_t,
                                                  const float* __restrict__ end_t,
                                                  float* __restrict__ out) {
  __shared__ float sm[2][1024];
  int b = blockIdx.x;
  int tid = threadIdx.x;
  int j = tid & 31;
  const float* base = Pc + b * 64 * 1024;
  f32x4 pre = *(const f32x4*)(base + tid * 4);    // chunk 0
  float u = __expf(start_t[j]) * Lexp[b * 2048 * 32 + j] * 32.f;
  float logacc = 0.f;
  for (int c = 0; c < 64; ++c) {
    *(f32x4*)(&sm[c & 1][tid * 4]) = pre;
    __syncthreads();
    if (c + 1 < 64) pre = *(const f32x4*)(base + (c + 1) * 1024 + tid * 4);
    const float* M = &sm[c & 1][0];
    float nu0 = 0.f, nu1 = 0.f, nu2 = 0.f, nu3 = 0.f;
    #pragma unroll
    for (int k = 0; k < 32; k += 4) {
      nu0 = fmaf(__shfl(u, k,     32), M[(k)     * 32 + j], nu0);
      nu1 = fmaf(__shfl(u, k + 1, 32), M[(k + 1) * 32 + j], nu1);
      nu2 = fmaf(__shfl(u, k + 2, 32), M[(k + 2) * 32 + j], nu2);
      nu3 = fmaf(__shfl(u, k + 3, 32), M[(k + 3) * 32 + j], nu3);
    }
    float nu = (nu0 + nu1) + (nu2 + nu3);
    float ssum = nu;
    #pragma unroll
    for (int o = 1; o < 32; o <<= 1) ssum += __shfl_xor(ssum, o, 32);
    u = nu * __builtin_amdgcn_rcpf(ssum);   // scale errors cancel telescopically
    logacc += __logf(ssum);
  }
  float term = u * __expf(end_t[j]);
  #pragma unroll
  for (int o = 1; o < 32; o <<= 1) term += __shfl_xor(term, o, 32);
  if (tid == 0)
    out[b] = logacc + logf(term) + (float)(2047.0 * 5.0 * 0.69314718055994530942);
}

extern "C" void kernel_launch(void* const* d_in, const int* in_sizes, int n_in,
                              void* d_out, int out_size, void* d_ws, size_t ws_size,
                              hipStream_t stream) {
  const int*   idx  = (const int*)d_in[0];
  const float* emb  = (const float*)d_in[1];
  const float* w1   = (const float*)d_in[2];
  const float* b1   = (const float*)d_in[3];
  const float* w2   = (const float*)d_in[4];
  const float* b2   = (const float*)d_in[5];
  const float* fcw  = (const float*)d_in[6];
  const float* fcb  = (const float*)d_in[7];
  const float* trn  = (const float*)d_in[8];
  const float* st   = (const float*)d_in[9];
  const float* en   = (const float*)d_in[10];

  char* ws = (char*)d_ws;
  __bf16* P     = (__bf16*)(ws + 0);           // 10,240,000 B
  float*  L     = (float*)(ws + 10240000);     // 16,777,216 B  (Lexp)
  float*  Pc    = (float*)(ws + 27017216);     // 16,777,216 B
  __bf16* WfB   = (__bf16*)(ws + 43794432);    //     81,920 B
  float*  G     = (float*)(ws + 43876352);     //     98,304 B
  float*  C0    = (float*)(ws + 43974656);     //     32,768 B
  float*  CT    = (float*)(ws + 44007424);     //     32,768 B
  float*  bias  = (float*)(ws + 44040192);     //        128 B
  float*  c0v   = (float*)(ws + 44040320);     //        128 B
  float*  cTv   = (float*)(ws + 44040448);     //        128 B
  float*  corr  = (float*)(ws + 44040576);     //     16,384 B
  // total ws need ~44.06 MB

  prep_g    <<<96,   256, 0, stream>>>(fcw, w2, G);
  prep_wf   <<<225,  256, 0, stream>>>(G, w1, b1, b2, fcw, fcb, WfB, C0, CT, bias, c0v, cTv);
  corr_k    <<<128,  256, 0, stream>>>(idx, emb, C0, CT, c0v, cTv, corr);
  p_table   <<<500,  256, 0, stream>>>(emb, WfB, P);
  logits_k  <<<2048, 256, 0, stream>>>(idx, P, bias, corr, L);
  crf_stage1<<<1024, 256, 0, stream>>>(L, trn, Pc);
  crf_stage2<<<64,   256, 0, stream>>>(L, Pc, st, en, (float*)d_out);
}

// Round 5
// 193.557 us; speedup vs baseline: 1.4048x; 1.2839x over previous
//
#include <hip/hip_runtime.h>
#include <hip/hip_bf16.h>

typedef float f32x4 __attribute__((ext_vector_type(4)));
typedef __bf16 bf16x8 __attribute__((ext_vector_type(8)));
typedef __bf16 bf16x4 __attribute__((ext_vector_type(4)));

// ---------------- transpose weights for contiguous prep dots ----------------
// w1t[k1][e][cp] = w1[cp][e][k1]; w2t[k2][cp][c] = w2[c][cp][k2]
__global__ __launch_bounds__(256) void transpose_w(const float* __restrict__ w1,
                                                   const float* __restrict__ w2,
                                                   float* __restrict__ w1t,
                                                   float* __restrict__ w2t) {
  int tid = blockIdx.x * 256 + threadIdx.x;   // 393216 threads
  if (tid < 196608) {
    float v = w1[tid];                // tid = cp*768 + e*3 + k1
    int k1 = tid % 3;
    int r = tid / 3;
    int e = r & 255;
    int cp = r >> 8;
    w1t[(k1 * 256 + e) * 256 + cp] = v;
  } else {
    int t2 = tid - 196608;            // t2 = c*768 + cp*3 + k2
    float v = w2[t2];
    int k2 = t2 % 3;
    int r = t2 / 3;
    int cp = r & 255;
    int c = r >> 8;
    w2t[(k2 * 256 + cp) * 256 + c] = v;
  }
}

// ---------------- G[k2][n][cp] = sum_c fc_w[n,c] * w2t[k2][cp][c] ----------
__global__ __launch_bounds__(256) void prep_g(const float* __restrict__ fcw,
                                              const float* __restrict__ w2t,
                                              float* __restrict__ G) {
  int tid = blockIdx.x * 256 + threadIdx.x;   // 24576 threads
  int cp = tid & 255;
  int rest = tid >> 8;       // 0..95
  int n = rest & 31;
  int k2 = rest >> 5;        // 0..2
  const float* wr = w2t + (k2 * 256 + cp) * 256;
  const float* fr = fcw + n * 256;
  float acc = 0.f;
  #pragma unroll 8
  for (int c = 0; c < 256; c += 4) {
    f32x4 a = *(const f32x4*)(fr + c);
    f32x4 bb = *(const f32x4*)(wr + c);
    acc = fmaf(a[0], bb[0], acc); acc = fmaf(a[1], bb[1], acc);
    acc = fmaf(a[2], bb[2], acc); acc = fmaf(a[3], bb[3], acc);
  }
  G[(k2 * 32 + n) * 256 + cp] = acc;
}

// ---------------- Wf (packed bf16 in MFMA B-frag layout), C0, CT, biases ----
__global__ __launch_bounds__(256) void prep_wf(const float* __restrict__ G,
                                               const float* __restrict__ w1t,
                                               const float* __restrict__ b1,
                                               const float* __restrict__ b2,
                                               const float* __restrict__ fcw,
                                               const float* __restrict__ fcb,
                                               __bf16* __restrict__ wfb,
                                               float* __restrict__ C0,
                                               float* __restrict__ CT,
                                               float* __restrict__ bias_tot,
                                               float* __restrict__ c0v,
                                               float* __restrict__ cTv) {
  int tid = blockIdx.x * 256 + threadIdx.x;
  if (tid < 40960) {                 // Wf part: tid = (e*5 + kk)*32 + n
    int n = tid & 31;
    int r = tid >> 5;                // 0..1279
    int kk = r % 5;
    int e = r / 5;
    float acc = 0.f;
    #pragma unroll
    for (int k2 = 0; k2 < 3; ++k2) {
      int k1 = kk - k2;
      if (k1 < 0 || k1 > 2) continue;
      const float* g = G + (k2 * 32 + n) * 256;
      const float* wr = w1t + (k1 * 256 + e) * 256;
      #pragma unroll 8
      for (int cp = 0; cp < 256; cp += 4) {
        f32x4 a = *(const f32x4*)(g + cp);
        f32x4 bb = *(const f32x4*)(wr + cp);
        acc = fmaf(a[0], bb[0], acc); acc = fmaf(a[1], bb[1], acc);
        acc = fmaf(a[2], bb[2], acc); acc = fmaf(a[3], bb[3], acc);
      }
    }
    // pack into B-frag layout for mfma_f32_16x16x32_bf16
    int j = kk * 32 + n;
    int jt = j >> 4, jl = j & 15;
    int et = e >> 5, el = e & 31;
    int lane = jl | ((el >> 3) << 4);
    int rr = el & 7;
    wfb[((jt * 8 + et) * 64 + lane) * 8 + rr] = (__bf16)acc;
  } else if (tid < 57344) {          // C0 / CT
    int t2 = tid - 40960;
    int which = (t2 >= 8192);
    if (which) t2 -= 8192;
    int n = t2 & 31;
    int e = t2 >> 5;
    const float* g = G + ((which ? 2 : 0) * 32 + n) * 256;
    int k1 = which ? 0 : 2;
    const float* wr = w1t + (k1 * 256 + e) * 256;
    float acc = 0.f;
    #pragma unroll 8
    for (int cp = 0; cp < 256; cp += 4) {
      f32x4 a = *(const f32x4*)(g + cp);
      f32x4 bb = *(const f32x4*)(wr + cp);
      acc = fmaf(a[0], bb[0], acc); acc = fmaf(a[1], bb[1], acc);
      acc = fmaf(a[2], bb[2], acc); acc = fmaf(a[3], bb[3], acc);
    }
    (which ? CT : C0)[n * 256 + e] = acc;
  } else if (tid < 57376) {          // biases
    int n = tid - 57344;
    float bt = fcb[n];
    for (int c = 0; c < 256; ++c) bt = fmaf(fcw[n * 256 + c], b2[c], bt);
    float s0 = 0.f, s1 = 0.f, s2 = 0.f;
    const float* g0 = G + (0 * 32 + n) * 256;
    const float* g1 = G + (1 * 32 + n) * 256;
    const float* g2 = G + (2 * 32 + n) * 256;
    for (int cp = 0; cp < 256; ++cp) {
      s0 = fmaf(g0[cp], b1[cp], s0);
      s1 = fmaf(g1[cp], b1[cp], s1);
      s2 = fmaf(g2[cp], b1[cp], s2);
    }
    bias_tot[n] = bt + s0 + s1 + s2;
    c0v[n] = s0;
    cTv[n] = s2;
  }
}

// ---------------- boundary corrections ----------------
__global__ __launch_bounds__(256) void corr_k(const int* __restrict__ idx,
                                              const float* __restrict__ emb,
                                              const float* __restrict__ C0,
                                              const float* __restrict__ CT,
                                              const float* __restrict__ c0v,
                                              const float* __restrict__ cTv,
                                              float* __restrict__ corr) {
  __shared__ float red[256];
  int b = blockIdx.x >> 1;
  int which = blockIdx.x & 1;
  int n = threadIdx.x & 31;
  int part = threadIdx.x >> 5;   // 0..7
  int v = idx[b * 2048 + (which ? 2047 : 0)];
  const float* C = which ? CT : C0;
  const float* er = emb + v * 256 + part * 32;
  const float* cr = C + n * 256 + part * 32;
  float s = 0.f;
  #pragma unroll
  for (int e = 0; e < 32; ++e) s = fmaf(cr[e], er[e], s);
  red[threadIdx.x] = s;
  __syncthreads();
  if (part == 0) {
    float tot = (which ? cTv : c0v)[n];
    #pragma unroll
    for (int p = 0; p < 8; ++p) tot += red[p * 32 + n];
    corr[(which * 64 + b) * 32 + n] = tot;
  }
}

// ---------------- P[v][kk][n] (bf16 MFMA GEMM, bf16 out) ----------------
__global__ __launch_bounds__(256) void p_table(const float* __restrict__ emb,
                                               const __bf16* __restrict__ wfb,
                                               __bf16* __restrict__ P) {
  int lane = threadIdx.x & 63;
  int mt = blockIdx.x * 4 + (threadIdx.x >> 6);  // 0..1999
  int ln = lane & 15;
  int q = lane >> 4;
  int m = mt * 16 + ln;
  f32x4 acc[10];
  #pragma unroll
  for (int jt = 0; jt < 10; ++jt) acc[jt] = (f32x4){0.f, 0.f, 0.f, 0.f};
  const float* arow = emb + m * 256 + q * 8;
  #pragma unroll
  for (int et = 0; et < 8; ++et) {
    f32x4 a0 = *(const f32x4*)(arow + et * 32);
    f32x4 a1 = *(const f32x4*)(arow + et * 32 + 4);
    bf16x8 af;
    af[0] = (__bf16)a0[0]; af[1] = (__bf16)a0[1];
    af[2] = (__bf16)a0[2]; af[3] = (__bf16)a0[3];
    af[4] = (__bf16)a1[0]; af[5] = (__bf16)a1[1];
    af[6] = (__bf16)a1[2]; af[7] = (__bf16)a1[3];
    #pragma unroll
    for (int jt = 0; jt < 10; ++jt) {
      bf16x8 bfr = *(const bf16x8*)(wfb + ((jt * 8 + et) * 64 + lane) * 8);
      acc[jt] = __builtin_amdgcn_mfma_f32_16x16x32_bf16(af, bfr, acc[jt], 0, 0, 0);
    }
  }
  #pragma unroll
  for (int jt = 0; jt < 10; ++jt) {
    __bf16* pp = P + (mt * 16 + q * 4) * 160 + jt * 16 + ln;
    pp[0]   = (__bf16)acc[jt][0];
    pp[160] = (__bf16)acc[jt][1];
    pp[320] = (__bf16)acc[jt][2];
    pp[480] = (__bf16)acc[jt][3];
  }
}

// ---------------- logits -> Lexp[b][t][n] = exp(logit) * 2^-5 ----------------
__global__ __launch_bounds__(256) void logits_k(const int* __restrict__ idx,
                                                const __bf16* __restrict__ P,
                                                const float* __restrict__ bias_tot,
                                                const float* __restrict__ corr,
                                                float* __restrict__ L) {
  int tid = blockIdx.x * 256 + threadIdx.x;    // 2^19 threads
  int q = tid & 7;
  int tp = (tid >> 3) & 1023;
  int b = tid >> 13;
  int t0 = tp * 2;
  const int* ib = idx + b * 2048;
  f32x4 bias = *(const f32x4*)(bias_tot + q * 4);
  f32x4 acc0 = bias, acc1 = bias;
  #pragma unroll
  for (int j = 0; j < 6; ++j) {
    int tt = t0 + j - 2;
    if (tt < 0 || tt > 2047) continue;
    int v = ib[tt];
    const __bf16* pr = P + v * 160 + q * 4;
    if (j < 5) {
      bf16x4 pv = *(const bf16x4*)(pr + j * 32);
      acc0[0] += (float)pv[0]; acc0[1] += (float)pv[1];
      acc0[2] += (float)pv[2]; acc0[3] += (float)pv[3];
    }
    if (j >= 1) {
      bf16x4 pv = *(const bf16x4*)(pr + (j - 1) * 32);
      acc1[0] += (float)pv[0]; acc1[1] += (float)pv[1];
      acc1[2] += (float)pv[2]; acc1[3] += (float)pv[3];
    }
  }
  if (t0 == 0)        acc0 -= *(const f32x4*)(corr + b * 32 + q * 4);
  if (t0 + 1 == 2047) acc1 -= *(const f32x4*)(corr + (64 + b) * 32 + q * 4);
  f32x4 r0, r1;
  r0[0] = __expf(acc0[0]) * 0.03125f;
  r0[1] = __expf(acc0[1]) * 0.03125f;
  r0[2] = __expf(acc0[2]) * 0.03125f;
  r0[3] = __expf(acc0[3]) * 0.03125f;
  r1[0] = __expf(acc1[0]) * 0.03125f;
  r1[1] = __expf(acc1[1]) * 0.03125f;
  r1[2] = __expf(acc1[2]) * 0.03125f;
  r1[3] = __expf(acc1[3]) * 0.03125f;
  float* Lb = L + (b * 2048 + t0) * 32 + q * 4;
  *(f32x4*)(Lb) = r0;
  *(f32x4*)(Lb + 32) = r1;
}

// ---------------- CRF stage 1: 32-step chunk transfer matrices (MFMA) --------
__global__ __launch_bounds__(256) void crf_stage1(const float* __restrict__ Lexp,
                                                  const float* __restrict__ trans,
                                                  float* __restrict__ Pc) {
  __shared__ __bf16 sl[4][32 * 40];   // wave-private S scratch, padded stride 40
  int lane = threadIdx.x & 63;
  int w = threadIdx.x >> 6;
  int chain = blockIdx.x * 4 + w;     // 0..4095
  int c = chain >> 6;                 // chunk 0..63
  int b = chain & 63;
  int ln = lane & 15;
  int q = lane >> 4;
  float tA0[8], tA1[8];
  #pragma unroll
  for (int e = 0; e < 8; ++e) {
    tA0[e] = __expf(trans[(q * 8 + e) * 32 + ln]);
    tA1[e] = __expf(trans[(q * 8 + e) * 32 + 16 + ln]);
  }
  bf16x8 bf0, bf1;
  #pragma unroll
  for (int e = 0; e < 8; ++e) {
    int k = q * 8 + e;
    bf0[e] = (k == ln) ? (__bf16)1.0f : (__bf16)0.0f;
    bf1[e] = (k == 16 + ln) ? (__bf16)1.0f : (__bf16)0.0f;
  }
  int tstart = c * 32 + 1;
  int nsteps = (c == 63) ? 31 : 32;
  const float* Le = Lexp + (b * 2048 + tstart) * 32;
  __bf16* myS = &sl[w][0];
  f32x4 c00, c01, c10, c11;
  float sc0 = Le[ln], sc1 = Le[ln + 16];
  for (int s = 0; s < nsteps; ++s) {
    float nsc0 = 0.f, nsc1 = 0.f;
    if (s + 1 < nsteps) {
      nsc0 = Le[(s + 1) * 32 + ln];
      nsc1 = Le[(s + 1) * 32 + ln + 16];
    }
    bf16x8 a0, a1;
    #pragma unroll
    for (int e = 0; e < 8; ++e) {
      a0[e] = (__bf16)(sc0 * tA0[e]);
      a1[e] = (__bf16)(sc1 * tA1[e]);
    }
    f32x4 z = {0.f, 0.f, 0.f, 0.f};
    c00 = __builtin_amdgcn_mfma_f32_16x16x32_bf16(a0, bf0, z, 0, 0, 0);
    c01 = __builtin_amdgcn_mfma_f32_16x16x32_bf16(a0, bf1, z, 0, 0, 0);
    c10 = __builtin_amdgcn_mfma_f32_16x16x32_bf16(a1, bf0, z, 0, 0, 0);
    c11 = __builtin_amdgcn_mfma_f32_16x16x32_bf16(a1, bf1, z, 0, 0, 0);
    if (s + 1 < nsteps) {
      bf16x4 w00, w01, w10, w11;
      #pragma unroll
      for (int r = 0; r < 4; ++r) {
        w00[r] = (__bf16)c00[r]; w01[r] = (__bf16)c01[r];
        w10[r] = (__bf16)c10[r]; w11[r] = (__bf16)c11[r];
      }
      *(bf16x4*)(myS + (ln) * 40      + q * 4)      = w00;
      *(bf16x4*)(myS + (16 + ln) * 40 + q * 4)      = w01;
      *(bf16x4*)(myS + (ln) * 40      + 16 + q * 4) = w10;
      *(bf16x4*)(myS + (16 + ln) * 40 + 16 + q * 4) = w11;
      bf0 = *(const bf16x8*)(myS + (ln) * 40 + q * 8);
      bf1 = *(const bf16x8*)(myS + (16 + ln) * 40 + q * 8);
    }
    sc0 = nsc0; sc1 = nsc1;
  }
  float* dst = Pc + ((b * 64 + c) * 32) * 32;
  *(f32x4*)(dst + (ln) * 32      + q * 4)      = c00;
  *(f32x4*)(dst + (16 + ln) * 32 + q * 4)      = c01;
  *(f32x4*)(dst + (ln) * 32      + 16 + q * 4) = c10;
  *(f32x4*)(dst + (16 + ln) * 32 + 16 + q * 4) = c11;
}

// ---------------- CRF combine-8: Pg[b][g] = M_{8g} * ... * M_{8g+7} ----------
// One wave per (b,g). Computes S = M^T products (new matrix on left as A-frag,
// loaded straight from Pc columns, prefetched 1 step ahead); S as B-frag via
// wave-private LDS transpose. Epilogue writes S^T = P_g.
__global__ __launch_bounds__(256) void crf_comb8(const float* __restrict__ Pc,
                                                 float* __restrict__ Pg) {
  __shared__ __bf16 sl[4][32 * 40];
  int lane = threadIdx.x & 63;
  int w = threadIdx.x >> 6;
  int wave = blockIdx.x * 4 + w;   // 0..511
  int b = wave >> 3;
  int g = wave & 7;
  int ln = lane & 15;
  int q = lane >> 4;
  const float* base = Pc + ((b * 64 + g * 8) * 32) * 32;
  float cur[16], nxt[16];
  #pragma unroll
  for (int e = 0; e < 8; ++e) {        // A = M^T: A[m][k] = M[k][m]
    cur[e]     = base[(q * 8 + e) * 32 + ln];
    cur[8 + e] = base[(q * 8 + e) * 32 + 16 + ln];
  }
  bf16x8 bf0, bf1;                     // S = I
  #pragma unroll
  for (int e = 0; e < 8; ++e) {
    int k = q * 8 + e;
    bf0[e] = (k == ln) ? (__bf16)1.0f : (__bf16)0.0f;
    bf1[e] = (k == 16 + ln) ? (__bf16)1.0f : (__bf16)0.0f;
  }
  __bf16* myS = &sl[w][0];
  f32x4 c00, c01, c10, c11;
  for (int j = 0; j < 8; ++j) {
    if (j < 7) {
      const float* mn = base + (j + 1) * 1024;
      #pragma unroll
      for (int e = 0; e < 8; ++e) {
        nxt[e]     = mn[(q * 8 + e) * 32 + ln];
        nxt[8 + e] = mn[(q * 8 + e) * 32 + 16 + ln];
      }
    }
    bf16x8 a0, a1;
    #pragma unroll
    for (int e = 0; e < 8; ++e) {
      a0[e] = (__bf16)cur[e];
      a1[e] = (__bf16)cur[8 + e];
    }
    f32x4 z = {0.f, 0.f, 0.f, 0.f};
    c00 = __builtin_amdgcn_mfma_f32_16x16x32_bf16(a0, bf0, z, 0, 0, 0);
    c01 = __builtin_amdgcn_mfma_f32_16x16x32_bf16(a0, bf1, z, 0, 0, 0);
    c10 = __builtin_amdgcn_mfma_f32_16x16x32_bf16(a1, bf0, z, 0, 0, 0);
    c11 = __builtin_amdgcn_mfma_f32_16x16x32_bf16(a1, bf1, z, 0, 0, 0);
    if (j < 7) {
      bf16x4 w00, w01, w10, w11;
      #pragma unroll
      for (int r = 0; r < 4; ++r) {
        w00[r] = (__bf16)c00[r]; w01[r] = (__bf16)c01[r];
        w10[r] = (__bf16)c10[r]; w11[r] = (__bf16)c11[r];
      }
      *(bf16x4*)(myS + (ln) * 40      + q * 4)      = w00;
      *(bf16x4*)(myS + (16 + ln) * 40 + q * 4)      = w01;
      *(bf16x4*)(myS + (ln) * 40      + 16 + q * 4) = w10;
      *(bf16x4*)(myS + (16 + ln) * 40 + 16 + q * 4) = w11;
      bf0 = *(const bf16x8*)(myS + (ln) * 40 + q * 8);
      bf1 = *(const bf16x8*)(myS + (16 + ln) * 40 + q * 8);
      #pragma unroll
      for (int e = 0; e < 16; ++e) cur[e] = nxt[e];
    }
  }
  float* dst = Pg + ((b * 8 + g) * 32) * 32;   // Pg[i][j] = S[j][i]
  *(f32x4*)(dst + (ln) * 32      + q * 4)      = c00;
  *(f32x4*)(dst + (16 + ln) * 32 + q * 4)      = c01;
  *(f32x4*)(dst + (ln) * 32      + 16 + q * 4) = c10;
  *(f32x4*)(dst + (16 + ln) * 32 + 16 + q * 4) = c11;
}

// ---------------- CRF final: 8 serial vec-mat steps, all matrices in LDS ----
__global__ __launch_bounds__(256) void crf_final(const float* __restrict__ Lexp,
                                                 const float* __restrict__ Pg,
                                                 const float* __restrict__ start_t,
                                                 const float* __restrict__ end_t,
                                                 float* __restrict__ out) {
  __shared__ float sm[8192];
  int b = blockIdx.x;
  int tid = threadIdx.x;
  int j = tid & 31;
  const float* base = Pg + b * 8192;
  #pragma unroll
  for (int g = 0; g < 8; ++g)
    *(f32x4*)(&sm[g * 1024 + tid * 4]) = *(const f32x4*)(base + g * 1024 + tid * 4);
  float u = __expf(start_t[j]) * Lexp[b * 2048 * 32 + j] * 32.f;
  __syncthreads();
  float logacc = 0.f;
  #pragma unroll
  for (int g = 0; g < 8; ++g) {
    const float* M = &sm[g * 1024];
    float nu0 = 0.f, nu1 = 0.f, nu2 = 0.f, nu3 = 0.f;
    #pragma unroll
    for (int k = 0; k < 32; k += 4) {
      nu0 = fmaf(__shfl(u, k,     32), M[(k)     * 32 + j], nu0);
      nu1 = fmaf(__shfl(u, k + 1, 32), M[(k + 1) * 32 + j], nu1);
      nu2 = fmaf(__shfl(u, k + 2, 32), M[(k + 2) * 32 + j], nu2);
      nu3 = fmaf(__shfl(u, k + 3, 32), M[(k + 3) * 32 + j], nu3);
    }
    float nu = (nu0 + nu1) + (nu2 + nu3);
    float ssum = nu;
    #pragma unroll
    for (int o = 1; o < 32; o <<= 1) ssum += __shfl_xor(ssum, o, 32);
    u = nu * __builtin_amdgcn_rcpf(ssum);   // scale errors cancel telescopically
    logacc += __logf(ssum);
  }
  float term = u * __expf(end_t[j]);
  #pragma unroll
  for (int o = 1; o < 32; o <<= 1) term += __shfl_xor(term, o, 32);
  if (tid == 0)
    out[b] = logacc + logf(term) + (float)(2047.0 * 5.0 * 0.69314718055994530942);
}

extern "C" void kernel_launch(void* const* d_in, const int* in_sizes, int n_in,
                              void* d_out, int out_size, void* d_ws, size_t ws_size,
                              hipStream_t stream) {
  const int*   idx  = (const int*)d_in[0];
  const float* emb  = (const float*)d_in[1];
  const float* w1   = (const float*)d_in[2];
  const float* b1   = (const float*)d_in[3];
  const float* w2   = (const float*)d_in[4];
  const float* b2   = (const float*)d_in[5];
  const float* fcw  = (const float*)d_in[6];
  const float* fcb  = (const float*)d_in[7];
  const float* trn  = (const float*)d_in[8];
  const float* st   = (const float*)d_in[9];
  const float* en   = (const float*)d_in[10];

  char* ws = (char*)d_ws;
  __bf16* P     = (__bf16*)(ws + 0);           // 10,240,000 B  (dead after logits_k)
  float*  Pg    = (float*)(ws + 0);            //  2,097,152 B  (reuses P space; comb8 runs after logits_k)
  float*  L     = (float*)(ws + 10240000);     // 16,777,216 B  (Lexp)
  float*  Pc    = (float*)(ws + 27017216);     // 16,777,216 B  (written by stage1, after preps)
  float*  w1t   = (float*)(ws + 27017216);     //    786,432 B  (reuses Pc space; dead before stage1)
  float*  w2t   = (float*)(ws + 27803648);     //    786,432 B  (ditto)
  __bf16* WfB   = (__bf16*)(ws + 43794432);    //     81,920 B
  float*  G     = (float*)(ws + 43876352);     //     98,304 B
  float*  C0    = (float*)(ws + 43974656);     //     32,768 B
  float*  CT    = (float*)(ws + 44007424);     //     32,768 B
  float*  bias  = (float*)(ws + 44040192);     //        128 B
  float*  c0v   = (float*)(ws + 44040320);     //        128 B
  float*  cTv   = (float*)(ws + 44040448);     //        128 B
  float*  corr  = (float*)(ws + 44040576);     //     16,384 B
  // total ws need ~44.06 MB (unchanged)

  transpose_w<<<1536, 256, 0, stream>>>(w1, w2, w1t, w2t);
  prep_g     <<<96,   256, 0, stream>>>(fcw, w2t, G);
  prep_wf    <<<225,  256, 0, stream>>>(G, w1t, b1, b2, fcw, fcb, WfB, C0, CT, bias, c0v, cTv);
  corr_k     <<<128,  256, 0, stream>>>(idx, emb, C0, CT, c0v, cTv, corr);
  p_table    <<<500,  256, 0, stream>>>(emb, WfB, P);
  logits_k   <<<2048, 256, 0, stream>>>(idx, P, bias, corr, L);
  crf_stage1 <<<1024, 256, 0, stream>>>(L, trn, Pc);
  crf_comb8  <<<128,  256, 0, stream>>>(Pc, Pg);
  crf_final  <<<64,   256, 0, stream>>>(L, Pg, st, en, (float*)d_out);
}

// Round 6
// 186.637 us; speedup vs baseline: 1.4569x; 1.0371x over previous
//
#include <hip/hip_runtime.h>
#include <hip/hip_bf16.h>

typedef float f32x4 __attribute__((ext_vector_type(4)));
typedef __bf16 bf16x8 __attribute__((ext_vector_type(8)));
typedef __bf16 bf16x4 __attribute__((ext_vector_type(4)));

// ---------------- transpose weights for contiguous prep dots ----------------
__global__ __launch_bounds__(256) void transpose_w(const float* __restrict__ w1,
                                                   const float* __restrict__ w2,
                                                   float* __restrict__ w1t,
                                                   float* __restrict__ w2t) {
  int tid = blockIdx.x * 256 + threadIdx.x;   // 393216 threads
  if (tid < 196608) {
    float v = w1[tid];                // tid = cp*768 + e*3 + k1
    int k1 = tid % 3;
    int r = tid / 3;
    int e = r & 255;
    int cp = r >> 8;
    w1t[(k1 * 256 + e) * 256 + cp] = v;
  } else {
    int t2 = tid - 196608;            // t2 = c*768 + cp*3 + k2
    float v = w2[t2];
    int k2 = t2 % 3;
    int r = t2 / 3;
    int cp = r & 255;
    int c = r >> 8;
    w2t[(k2 * 256 + cp) * 256 + c] = v;
  }
}

// ---------------- G[k2][n][cp] = sum_c fc_w[n,c] * w2t[k2][cp][c] ----------
__global__ __launch_bounds__(256) void prep_g(const float* __restrict__ fcw,
                                              const float* __restrict__ w2t,
                                              float* __restrict__ G) {
  int tid = blockIdx.x * 256 + threadIdx.x;   // 24576 threads
  int cp = tid & 255;
  int rest = tid >> 8;       // 0..95
  int n = rest & 31;
  int k2 = rest >> 5;        // 0..2
  const float* wr = w2t + (k2 * 256 + cp) * 256;
  const float* fr = fcw + n * 256;
  float acc = 0.f;
  #pragma unroll 8
  for (int c = 0; c < 256; c += 4) {
    f32x4 a = *(const f32x4*)(fr + c);
    f32x4 bb = *(const f32x4*)(wr + c);
    acc = fmaf(a[0], bb[0], acc); acc = fmaf(a[1], bb[1], acc);
    acc = fmaf(a[2], bb[2], acc); acc = fmaf(a[3], bb[3], acc);
  }
  G[(k2 * 32 + n) * 256 + cp] = acc;
}

// ---------------- Wf (packed bf16 in MFMA B-frag layout), C0, CT, biases ----
__global__ __launch_bounds__(256) void prep_wf(const float* __restrict__ G,
                                               const float* __restrict__ w1t,
                                               const float* __restrict__ b1,
                                               const float* __restrict__ b2,
                                               const float* __restrict__ fcw,
                                               const float* __restrict__ fcb,
                                               __bf16* __restrict__ wfb,
                                               float* __restrict__ C0,
                                               float* __restrict__ CT,
                                               float* __restrict__ bias_tot,
                                               float* __restrict__ c0v,
                                               float* __restrict__ cTv) {
  int tid = blockIdx.x * 256 + threadIdx.x;
  if (tid < 40960) {                 // tid = (e*5 + kk)*32 + n
    int n = tid & 31;
    int r = tid >> 5;
    int kk = r % 5;
    int e = r / 5;
    float acc = 0.f;
    #pragma unroll
    for (int k2 = 0; k2 < 3; ++k2) {
      int k1 = kk - k2;
      if (k1 < 0 || k1 > 2) continue;
      const float* g = G + (k2 * 32 + n) * 256;
      const float* wr = w1t + (k1 * 256 + e) * 256;
      #pragma unroll 8
      for (int cp = 0; cp < 256; cp += 4) {
        f32x4 a = *(const f32x4*)(g + cp);
        f32x4 bb = *(const f32x4*)(wr + cp);
        acc = fmaf(a[0], bb[0], acc); acc = fmaf(a[1], bb[1], acc);
        acc = fmaf(a[2], bb[2], acc); acc = fmaf(a[3], bb[3], acc);
      }
    }
    int j = kk * 32 + n;
    int jt = j >> 4, jl = j & 15;
    int et = e >> 5, el = e & 31;
    int lane = jl | ((el >> 3) << 4);
    int rr = el & 7;
    wfb[((jt * 8 + et) * 64 + lane) * 8 + rr] = (__bf16)acc;
  } else if (tid < 57344) {          // C0 / CT
    int t2 = tid - 40960;
    int which = (t2 >= 8192);
    if (which) t2 -= 8192;
    int n = t2 & 31;
    int e = t2 >> 5;
    const float* g = G + ((which ? 2 : 0) * 32 + n) * 256;
    int k1 = which ? 0 : 2;
    const float* wr = w1t + (k1 * 256 + e) * 256;
    float acc = 0.f;
    #pragma unroll 8
    for (int cp = 0; cp < 256; cp += 4) {
      f32x4 a = *(const f32x4*)(g + cp);
      f32x4 bb = *(const f32x4*)(wr + cp);
      acc = fmaf(a[0], bb[0], acc); acc = fmaf(a[1], bb[1], acc);
      acc = fmaf(a[2], bb[2], acc); acc = fmaf(a[3], bb[3], acc);
    }
    (which ? CT : C0)[n * 256 + e] = acc;
  } else if (tid < 57376) {          // biases
    int n = tid - 57344;
    float bt = fcb[n];
    for (int c = 0; c < 256; ++c) bt = fmaf(fcw[n * 256 + c], b2[c], bt);
    float s0 = 0.f, s1 = 0.f, s2 = 0.f;
    const float* g0 = G + (0 * 32 + n) * 256;
    const float* g1 = G + (1 * 32 + n) * 256;
    const float* g2 = G + (2 * 32 + n) * 256;
    for (int cp = 0; cp < 256; ++cp) {
      s0 = fmaf(g0[cp], b1[cp], s0);
      s1 = fmaf(g1[cp], b1[cp], s1);
      s2 = fmaf(g2[cp], b1[cp], s2);
    }
    bias_tot[n] = bt + s0 + s1 + s2;
    c0v[n] = s0;
    cTv[n] = s2;
  }
}

// ---------------- P table (MFMA) + boundary corrections, one kernel ----------
__global__ __launch_bounds__(256) void ptab_corr(const float* __restrict__ emb,
                                                 const __bf16* __restrict__ wfb,
                                                 __bf16* __restrict__ P,
                                                 const int* __restrict__ idx,
                                                 const float* __restrict__ C0,
                                                 const float* __restrict__ CT,
                                                 const float* __restrict__ c0v,
                                                 const float* __restrict__ cTv,
                                                 float* __restrict__ corr) {
  __shared__ float red[256];
  if (blockIdx.x < 500) {            // ---- p_table part ----
    int lane = threadIdx.x & 63;
    int mt = blockIdx.x * 4 + (threadIdx.x >> 6);  // 0..1999
    int ln = lane & 15;
    int q = lane >> 4;
    int m = mt * 16 + ln;
    f32x4 acc[10];
    #pragma unroll
    for (int jt = 0; jt < 10; ++jt) acc[jt] = (f32x4){0.f, 0.f, 0.f, 0.f};
    const float* arow = emb + m * 256 + q * 8;
    #pragma unroll
    for (int et = 0; et < 8; ++et) {
      f32x4 a0 = *(const f32x4*)(arow + et * 32);
      f32x4 a1 = *(const f32x4*)(arow + et * 32 + 4);
      bf16x8 af;
      af[0] = (__bf16)a0[0]; af[1] = (__bf16)a0[1];
      af[2] = (__bf16)a0[2]; af[3] = (__bf16)a0[3];
      af[4] = (__bf16)a1[0]; af[5] = (__bf16)a1[1];
      af[6] = (__bf16)a1[2]; af[7] = (__bf16)a1[3];
      #pragma unroll
      for (int jt = 0; jt < 10; ++jt) {
        bf16x8 bfr = *(const bf16x8*)(wfb + ((jt * 8 + et) * 64 + lane) * 8);
        acc[jt] = __builtin_amdgcn_mfma_f32_16x16x32_bf16(af, bfr, acc[jt], 0, 0, 0);
      }
    }
    #pragma unroll
    for (int jt = 0; jt < 10; ++jt) {
      __bf16* pp = P + (mt * 16 + q * 4) * 160 + jt * 16 + ln;
      pp[0]   = (__bf16)acc[jt][0];
      pp[160] = (__bf16)acc[jt][1];
      pp[320] = (__bf16)acc[jt][2];
      pp[480] = (__bf16)acc[jt][3];
    }
  } else {                           // ---- corr part (128 blocks) ----
    int bid = blockIdx.x - 500;
    int b = bid >> 1;
    int which = bid & 1;
    int n = threadIdx.x & 31;
    int part = threadIdx.x >> 5;   // 0..7
    int v = idx[b * 2048 + (which ? 2047 : 0)];
    const float* C = which ? CT : C0;
    const float* er = emb + v * 256 + part * 32;
    const float* cr = C + n * 256 + part * 32;
    float s = 0.f;
    #pragma unroll
    for (int e = 0; e < 32; ++e) s = fmaf(cr[e], er[e], s);
    red[threadIdx.x] = s;
    __syncthreads();
    if (part == 0) {
      float tot = (which ? cTv : c0v)[n];
      #pragma unroll
      for (int p = 0; p < 8; ++p) tot += red[p * 32 + n];
      corr[(which * 64 + b) * 32 + n] = tot;
    }
  }
}

// ---------------- logits -> Lexp[b][t][n] = exp(logit)*2^-5  (bf16 out) ------
__global__ __launch_bounds__(256) void logits_k(const int* __restrict__ idx,
                                                const __bf16* __restrict__ P,
                                                const float* __restrict__ bias_tot,
                                                const float* __restrict__ corr,
                                                __bf16* __restrict__ L) {
  int tid = blockIdx.x * 256 + threadIdx.x;    // 2^19 threads
  int q = tid & 7;
  int tp = (tid >> 3) & 1023;
  int b = tid >> 13;
  int t0 = tp * 2;
  const int* ib = idx + b * 2048;
  f32x4 bias = *(const f32x4*)(bias_tot + q * 4);
  f32x4 acc0 = bias, acc1 = bias;
  #pragma unroll
  for (int j = 0; j < 6; ++j) {
    int tt = t0 + j - 2;
    if (tt < 0 || tt > 2047) continue;
    int v = ib[tt];
    const __bf16* pr = P + v * 160 + q * 4;
    if (j < 5) {
      bf16x4 pv = *(const bf16x4*)(pr + j * 32);
      acc0[0] += (float)pv[0]; acc0[1] += (float)pv[1];
      acc0[2] += (float)pv[2]; acc0[3] += (float)pv[3];
    }
    if (j >= 1) {
      bf16x4 pv = *(const bf16x4*)(pr + (j - 1) * 32);
      acc1[0] += (float)pv[0]; acc1[1] += (float)pv[1];
      acc1[2] += (float)pv[2]; acc1[3] += (float)pv[3];
    }
  }
  if (t0 == 0)        acc0 -= *(const f32x4*)(corr + b * 32 + q * 4);
  if (t0 + 1 == 2047) acc1 -= *(const f32x4*)(corr + (64 + b) * 32 + q * 4);
  bf16x4 r0, r1;
  r0[0] = (__bf16)(__expf(acc0[0]) * 0.03125f);
  r0[1] = (__bf16)(__expf(acc0[1]) * 0.03125f);
  r0[2] = (__bf16)(__expf(acc0[2]) * 0.03125f);
  r0[3] = (__bf16)(__expf(acc0[3]) * 0.03125f);
  r1[0] = (__bf16)(__expf(acc1[0]) * 0.03125f);
  r1[1] = (__bf16)(__expf(acc1[1]) * 0.03125f);
  r1[2] = (__bf16)(__expf(acc1[2]) * 0.03125f);
  r1[3] = (__bf16)(__expf(acc1[3]) * 0.03125f);
  __bf16* Lb = L + (b * 2048 + t0) * 32 + q * 4;
  *(bf16x4*)(Lb) = r0;
  *(bf16x4*)(Lb + 32) = r1;
}

// ---------------- CRF stage 1: 32-step chunk transfer matrices (MFMA) --------
// S <- (D_t * Texp^T) * S, S0 = I.  Scales batch-loaded 8 steps ahead.
// Output PcB: per (b,c), lane-ordered bf16 A-frags for crf_tail:
//   PcB[((b*64+c)*64 + lane)*16 + 0..7]  = S[ln][q*8+e]      (A rows 0..15)
//   PcB[((b*64+c)*64 + lane)*16 + 8..15] = S[16+ln][q*8+e]   (A rows 16..31)
__global__ __launch_bounds__(256) void crf_stage1(const __bf16* __restrict__ Lexp,
                                                  const float* __restrict__ trans,
                                                  __bf16* __restrict__ PcB) {
  __shared__ __bf16 sl[4][32 * 40];   // wave-private S scratch, padded stride 40
  int lane = threadIdx.x & 63;
  int w = threadIdx.x >> 6;
  int chain = blockIdx.x * 4 + w;     // 0..4095
  int c = chain >> 6;                 // chunk 0..63
  int b = chain & 63;
  int ln = lane & 15;
  int q = lane >> 4;
  float tA0[8], tA1[8];
  #pragma unroll
  for (int e = 0; e < 8; ++e) {
    tA0[e] = __expf(trans[(q * 8 + e) * 32 + ln]);
    tA1[e] = __expf(trans[(q * 8 + e) * 32 + 16 + ln]);
  }
  bf16x8 bf0, bf1;                    // S = I
  #pragma unroll
  for (int e = 0; e < 8; ++e) {
    int k = q * 8 + e;
    bf0[e] = (k == ln) ? (__bf16)1.0f : (__bf16)0.0f;
    bf1[e] = (k == 16 + ln) ? (__bf16)1.0f : (__bf16)0.0f;
  }
  int tstart = c * 32 + 1;
  int total = (c == 63) ? 31 : 32;
  const __bf16* Le = Lexp + (b * 2048 + tstart) * 32;
  __bf16* myS = &sl[w][0];

  auto step = [&](float sc0, float sc1) {
    bf16x8 a0, a1;
    #pragma unroll
    for (int e = 0; e < 8; ++e) {
      a0[e] = (__bf16)(sc0 * tA0[e]);
      a1[e] = (__bf16)(sc1 * tA1[e]);
    }
    f32x4 z = {0.f, 0.f, 0.f, 0.f};
    f32x4 c00 = __builtin_amdgcn_mfma_f32_16x16x32_bf16(a0, bf0, z, 0, 0, 0);
    f32x4 c01 = __builtin_amdgcn_mfma_f32_16x16x32_bf16(a0, bf1, z, 0, 0, 0);
    f32x4 c10 = __builtin_amdgcn_mfma_f32_16x16x32_bf16(a1, bf0, z, 0, 0, 0);
    f32x4 c11 = __builtin_amdgcn_mfma_f32_16x16x32_bf16(a1, bf1, z, 0, 0, 0);
    bf16x4 w00, w01, w10, w11;        // myS[col*40+row] = S'[row][col]
    #pragma unroll
    for (int r = 0; r < 4; ++r) {
      w00[r] = (__bf16)c00[r]; w01[r] = (__bf16)c01[r];
      w10[r] = (__bf16)c10[r]; w11[r] = (__bf16)c11[r];
    }
    *(bf16x4*)(myS + (ln) * 40      + q * 4)      = w00;
    *(bf16x4*)(myS + (16 + ln) * 40 + q * 4)      = w01;
    *(bf16x4*)(myS + (ln) * 40      + 16 + q * 4) = w10;
    *(bf16x4*)(myS + (16 + ln) * 40 + 16 + q * 4) = w11;
    bf0 = *(const bf16x8*)(myS + (ln) * 40 + q * 8);
    bf1 = *(const bf16x8*)(myS + (16 + ln) * 40 + q * 8);
  };

  float s0[8], s1[8];
  #pragma unroll
  for (int i = 0; i < 8; ++i) {
    s0[i] = (float)Le[i * 32 + ln];
    s1[i] = (float)Le[i * 32 + 16 + ln];
  }
  int nbatch = total >> 3;   // 4 (c<63) or 3 (c==63)
  int rem = total & 7;       // 0 or 7
  for (int bt = 0; bt < nbatch; ++bt) {
    float n0[8], n1[8];
    bool more = (bt + 1 < nbatch) || (rem != 0 && bt + 1 == nbatch);
    if (more) {
      int bs = (bt + 1) * 8;
      #pragma unroll
      for (int i = 0; i < 8; ++i) {
        int k = bs + i; if (k >= total) k = total - 1;
        n0[i] = (float)Le[k * 32 + ln];
        n1[i] = (float)Le[k * 32 + 16 + ln];
      }
    }
    #pragma unroll
    for (int s = 0; s < 8; ++s) step(s0[s], s1[s]);
    #pragma unroll
    for (int i = 0; i < 8; ++i) { s0[i] = n0[i]; s1[i] = n1[i]; }
  }
  if (rem) {
    #pragma unroll
    for (int s = 0; s < 7; ++s) step(s0[s], s1[s]);
  }
  // A-frag-ready output: o0[e] = S[ln][q*8+e] = myS[(q*8+e)*40 + ln]
  bf16x8 o0, o1;
  #pragma unroll
  for (int e = 0; e < 8; ++e) {
    o0[e] = myS[(q * 8 + e) * 40 + ln];
    o1[e] = myS[(q * 8 + e) * 40 + 16 + ln];
  }
  __bf16* dst = PcB + ((b * 64 + c) * 64 + lane) * 16;
  *(bf16x8*)(dst)     = o0;
  *(bf16x8*)(dst + 8) = o1;
}

// ---------------- CRF tail: group products (MFMA, 8 waves) + serial combine --
__global__ __launch_bounds__(512) void crf_tail(const __bf16* __restrict__ Lexp,
                                                const __bf16* __restrict__ PcB,
                                                const float* __restrict__ start_t,
                                                const float* __restrict__ end_t,
                                                float* __restrict__ out) {
  __shared__ float sg[8][1024];       // 8 group-product matrices, M[i][j]
  __shared__ __bf16 sl[8][32 * 40];   // per-wave transpose scratch
  int b = blockIdx.x;
  int tid = threadIdx.x;
  int lane = tid & 63;
  int g = tid >> 6;                   // wave = group 0..7
  int ln = lane & 15;
  int q = lane >> 4;
  const __bf16* base = PcB + ((b * 64 + g * 8) * 64) * 16;
  bf16x8 a0 = *(const bf16x8*)(base + lane * 16);
  bf16x8 a1 = *(const bf16x8*)(base + lane * 16 + 8);
  bf16x8 bf0, bf1;                    // S = I
  #pragma unroll
  for (int e = 0; e < 8; ++e) {
    int k = q * 8 + e;
    bf0[e] = (k == ln) ? (__bf16)1.0f : (__bf16)0.0f;
    bf1[e] = (k == 16 + ln) ? (__bf16)1.0f : (__bf16)0.0f;
  }
  __bf16* myS = &sl[g][0];
  f32x4 c00, c01, c10, c11;
  for (int j = 0; j < 8; ++j) {
    bf16x8 na0, na1;
    if (j < 7) {
      const __bf16* nb = base + (j + 1) * 1024 + lane * 16;
      na0 = *(const bf16x8*)(nb);
      na1 = *(const bf16x8*)(nb + 8);
    }
    f32x4 z = {0.f, 0.f, 0.f, 0.f};
    c00 = __builtin_amdgcn_mfma_f32_16x16x32_bf16(a0, bf0, z, 0, 0, 0);
    c01 = __builtin_amdgcn_mfma_f32_16x16x32_bf16(a0, bf1, z, 0, 0, 0);
    c10 = __builtin_amdgcn_mfma_f32_16x16x32_bf16(a1, bf0, z, 0, 0, 0);
    c11 = __builtin_amdgcn_mfma_f32_16x16x32_bf16(a1, bf1, z, 0, 0, 0);
    if (j < 7) {
      bf16x4 w00, w01, w10, w11;
      #pragma unroll
      for (int r = 0; r < 4; ++r) {
        w00[r] = (__bf16)c00[r]; w01[r] = (__bf16)c01[r];
        w10[r] = (__bf16)c10[r]; w11[r] = (__bf16)c11[r];
      }
      *(bf16x4*)(myS + (ln) * 40      + q * 4)      = w00;
      *(bf16x4*)(myS + (16 + ln) * 40 + q * 4)      = w01;
      *(bf16x4*)(myS + (ln) * 40      + 16 + q * 4) = w10;
      *(bf16x4*)(myS + (16 + ln) * 40 + 16 + q * 4) = w11;
      bf0 = *(const bf16x8*)(myS + (ln) * 40 + q * 8);
      bf1 = *(const bf16x8*)(myS + (16 + ln) * 40 + q * 8);
      a0 = na0; a1 = na1;
    }
  }
  // sg[g][i*32+j] = M[i][j] = S[j][i]
  #pragma unroll
  for (int r = 0; r < 4; ++r) {
    sg[g][(ln) * 32      + q * 4 + r]      = c00[r];
    sg[g][(16 + ln) * 32 + q * 4 + r]      = c01[r];
    sg[g][(ln) * 32      + 16 + q * 4 + r] = c10[r];
    sg[g][(16 + ln) * 32 + 16 + q * 4 + r] = c11[r];
  }
  int j2 = tid & 31;
  float u = __expf(start_t[j2]) * (float)Lexp[b * 2048 * 32 + j2] * 32.f;
  __syncthreads();
  float logacc = 0.f;
  #pragma unroll
  for (int gg = 0; gg < 8; ++gg) {
    const float* M = &sg[gg][0];
    float nu0 = 0.f, nu1 = 0.f, nu2 = 0.f, nu3 = 0.f;
    #pragma unroll
    for (int k = 0; k < 32; k += 4) {
      nu0 = fmaf(__shfl(u, k,     32), M[(k)     * 32 + j2], nu0);
      nu1 = fmaf(__shfl(u, k + 1, 32), M[(k + 1) * 32 + j2], nu1);
      nu2 = fmaf(__shfl(u, k + 2, 32), M[(k + 2) * 32 + j2], nu2);
      nu3 = fmaf(__shfl(u, k + 3, 32), M[(k + 3) * 32 + j2], nu3);
    }
    float nu = (nu0 + nu1) + (nu2 + nu3);
    float ssum = nu;
    #pragma unroll
    for (int o = 1; o < 32; o <<= 1) ssum += __shfl_xor(ssum, o, 32);
    u = nu * __builtin_amdgcn_rcpf(ssum);   // scale errors cancel telescopically
    logacc += __logf(ssum);
  }
  float term = u * __expf(end_t[j2]);
  #pragma unroll
  for (int o = 1; o < 32; o <<= 1) term += __shfl_xor(term, o, 32);
  if (tid == 0)
    out[b] = logacc + logf(term) + (float)(2047.0 * 5.0 * 0.69314718055994530942);
}

extern "C" void kernel_launch(void* const* d_in, const int* in_sizes, int n_in,
                              void* d_out, int out_size, void* d_ws, size_t ws_size,
                              hipStream_t stream) {
  const int*   idx  = (const int*)d_in[0];
  const float* emb  = (const float*)d_in[1];
  const float* w1   = (const float*)d_in[2];
  const float* b1   = (const float*)d_in[3];
  const float* w2   = (const float*)d_in[4];
  const float* b2   = (const float*)d_in[5];
  const float* fcw  = (const float*)d_in[6];
  const float* fcb  = (const float*)d_in[7];
  const float* trn  = (const float*)d_in[8];
  const float* st   = (const float*)d_in[9];
  const float* en   = (const float*)d_in[10];

  char* ws = (char*)d_ws;
  __bf16* P     = (__bf16*)(ws + 0);           // 10,240,000 B
  __bf16* L     = (__bf16*)(ws + 10240000);    //  8,388,608 B  (Lexp, bf16)
  __bf16* PcB   = (__bf16*)(ws + 18628608);    //  8,388,608 B  (A-frag chunk matrices)
  float*  w1t   = (float*)(ws + 27017216);     //    786,432 B
  float*  w2t   = (float*)(ws + 27803648);     //    786,432 B
  __bf16* WfB   = (__bf16*)(ws + 43794432);    //     81,920 B
  float*  G     = (float*)(ws + 43876352);     //     98,304 B
  float*  C0    = (float*)(ws + 43974656);     //     32,768 B
  float*  CT    = (float*)(ws + 44007424);     //     32,768 B
  float*  bias  = (float*)(ws + 44040192);     //        128 B
  float*  c0v   = (float*)(ws + 44040320);     //        128 B
  float*  cTv   = (float*)(ws + 44040448);     //        128 B
  float*  corr  = (float*)(ws + 44040576);     //     16,384 B

  transpose_w<<<1536, 256, 0, stream>>>(w1, w2, w1t, w2t);
  prep_g     <<<96,   256, 0, stream>>>(fcw, w2t, G);
  prep_wf    <<<225,  256, 0, stream>>>(G, w1t, b1, b2, fcw, fcb, WfB, C0, CT, bias, c0v, cTv);
  ptab_corr  <<<628,  256, 0, stream>>>(emb, WfB, P, idx, C0, CT, c0v, cTv, corr);
  logits_k   <<<2048, 256, 0, stream>>>(idx, P, bias, corr, L);
  crf_stage1 <<<1024, 256, 0, stream>>>(L, trn, PcB);
  crf_tail   <<<64,   512, 0, stream>>>(L, PcB, st, en, (float*)d_out);
}